// Round 7
// baseline (303.729 us; speedup 1.0000x reference)
//
#include <hip/hip_runtime.h>

#define N_NODES 100000
#define N_EDGES 600000
#define DIM 128

typedef __attribute__((ext_vector_type(8))) short bf16x8;
typedef __attribute__((ext_vector_type(4))) float f32x4;

typedef __attribute__((address_space(1))) const unsigned int g_u32;
typedef __attribute__((address_space(3))) unsigned int l_u32;
__device__ __forceinline__ void stage16(const void* g, void* l) {
  __builtin_amdgcn_global_load_lds((g_u32*)g, (l_u32*)l, 16, 0, 0);
}

__device__ __forceinline__ unsigned short f32_to_bf16_rn(float f) {
  unsigned int u = __builtin_bit_cast(unsigned int, f);
  unsigned int r = (u + 0x7FFFu + ((u >> 16) & 1u)) >> 16;
  return (unsigned short)r;
}
__device__ __forceinline__ float bf16_to_f32(unsigned short h) {
  return __builtin_bit_cast(float, (unsigned int)h << 16);
}

// pack one f32 into u32 = (hi_bf16 << 16) | lo_bf16, hi=rn(v), lo=rn(v-hi)
__device__ __forceinline__ unsigned int pack_hl(float v) {
  const unsigned int u = __builtin_bit_cast(unsigned int, v);
  const unsigned int r1 = u + 0x7FFFu + ((u >> 16) & 1u);
  const unsigned int hb = r1 & 0xFFFF0000u;  // bf(hi) bits
  const float fl = v - __builtin_bit_cast(float, hb);
  const unsigned int u2 = __builtin_bit_cast(unsigned int, fl);
  const unsigned int r2 = (u2 + 0x7FFFu + ((u2 >> 16) & 1u)) >> 16;
  return hb | (r2 & 0xFFFFu);
}

// ---------------- pack BOTH layers' weights into MFMA fragment order -------
// per layer: g-tile sequence (4096 shorts): [Wl_hi k0-31, Wl_lo k0-31, ...,
// Wr_hi..., Wr_lo...]; packed[((g*8+nt)*64+l)*8+j]
__global__ __launch_bounds__(256) void pack_w_k(
    const float* __restrict__ Wl0, const float* __restrict__ Wr0,
    const float* __restrict__ Wl1, const float* __restrict__ Wr1,
    unsigned short* __restrict__ P0, unsigned short* __restrict__ P1) {
  const int gid = blockIdx.x * 256 + threadIdx.x;  // 0..131071
  const int layer = gid >> 16;
  const int idx = gid & 65535;
  const int j = idx & 7;
  const int l = (idx >> 3) & 63;
  const int nt = (idx >> 9) & 7;
  const int g = idx >> 12;
  const int k = (((g >> 1) & 3) << 5) + ((l >> 4) << 3) + j;
  const int n = (nt << 4) + (l & 15);
  const float* W = layer ? ((g < 8) ? Wl1 : Wr1) : ((g < 8) ? Wl0 : Wr0);
  const float w = W[k * 128 + n];
  const unsigned short h = f32_to_bf16_rn(w);
  const unsigned short o = (g & 1) ? f32_to_bf16_rn(w - bf16_to_f32(h)) : h;
  (layer ? P1 : P0)[idx] = o;
}

// ---------------- CSR build ----------------
__global__ void hist_k(const int* __restrict__ dst, int* __restrict__ deg) {
  int e = blockIdx.x * blockDim.x + threadIdx.x;
  if (e < N_EDGES) atomicAdd(&deg[dst[e]], 1);
}

__global__ __launch_bounds__(1024) void scan1_k(const int* __restrict__ deg,
                                                int* __restrict__ incl,
                                                int* __restrict__ bsum) {
  __shared__ int wsum[16];
  const int t = threadIdx.x, lane = t & 63, w = t >> 6;
  const int gi = blockIdx.x * 1024 + t;
  int v = (gi < N_NODES) ? deg[gi] : 0;
  int s = v;
#pragma unroll
  for (int off = 1; off < 64; off <<= 1) {
    int u = __shfl_up(s, off);
    if (lane >= off) s += u;
  }
  if (lane == 63) wsum[w] = s;
  __syncthreads();
  if (t < 16) {
    int ws = wsum[t];
#pragma unroll
    for (int off = 1; off < 16; off <<= 1) {
      int u = __shfl_up(ws, off);
      if (t >= off) ws += u;
    }
    wsum[t] = ws;
  }
  __syncthreads();
  const int val = s + (w ? wsum[w - 1] : 0);
  if (gi < N_NODES) incl[gi] = val;
  if (t == 1023) bsum[blockIdx.x] = val;
}

__global__ void scan2_k(const int* __restrict__ bsum, int* __restrict__ boffs,
                        int nb) {
  __shared__ int w0;
  const int t = threadIdx.x;  // 128 threads
  int v = (t < nb) ? bsum[t] : 0;
  int s = v;
#pragma unroll
  for (int off = 1; off < 64; off <<= 1) {
    int u = __shfl_up(s, off);
    if ((t & 63) >= off) s += u;
  }
  if (t == 63) w0 = s;
  __syncthreads();
  const int excl = s - v + ((t >> 6) ? w0 : 0);
  if (t < nb) boffs[t] = excl;
}

__global__ __launch_bounds__(1024) void scan3_k(const int* __restrict__ deg,
                                                const int* __restrict__ incl,
                                                const int* __restrict__ boffs,
                                                int* __restrict__ rowptr,
                                                int* __restrict__ head) {
  const int gi = blockIdx.x * 1024 + threadIdx.x;
  if (gi < N_NODES) {
    const int e = incl[gi] - deg[gi] + boffs[blockIdx.x];
    rowptr[gi] = e;
    head[gi] = e;
  }
  if (gi == 0) rowptr[N_NODES] = N_EDGES;
}

__global__ void fill_k(const int* __restrict__ src, const int* __restrict__ dst,
                       int* __restrict__ head, int* __restrict__ col) {
  int e = blockIdx.x * blockDim.x + threadIdx.x;
  if (e < N_EDGES) {
    int p = atomicAdd(&head[dst[e]], 1);
    col[p] = src[e];
  }
}

// ---------------- fragment unpack helpers ----------------
__device__ __forceinline__ void unpack_pk(uint4 p0, uint4 p1, bf16x8& hi,
                                          bf16x8& lo) {
  const unsigned int u[8] = {p0.x, p0.y, p0.z, p0.w, p1.x, p1.y, p1.z, p1.w};
  uint4 hw, lw;
  unsigned int* hp = &hw.x;
  unsigned int* lp = &lw.x;
#pragma unroll
  for (int w = 0; w < 4; ++w) {
    hp[w] = __builtin_amdgcn_perm(u[2 * w + 1], u[2 * w], 0x07060302u);
    lp[w] = __builtin_amdgcn_perm(u[2 * w + 1], u[2 * w], 0x05040100u);
  }
  hi = __builtin_bit_cast(bf16x8, hw);
  lo = __builtin_bit_cast(bf16x8, lw);
}

__device__ __forceinline__ void split_f32(uint4 p0, uint4 p1, bf16x8& hi,
                                          bf16x8& lo) {
  const unsigned int u[8] = {p0.x, p0.y, p0.z, p0.w, p1.x, p1.y, p1.z, p1.w};
  unsigned int hb[8], l16[8];
#pragma unroll
  for (int e = 0; e < 8; ++e) {
    const unsigned int r1 = u[e] + 0x7FFFu + ((u[e] >> 16) & 1u);
    hb[e] = r1 & 0xFFFF0000u;
    const float fl = __builtin_bit_cast(float, u[e]) -
                     __builtin_bit_cast(float, hb[e]);
    const unsigned int u2 = __builtin_bit_cast(unsigned int, fl);
    l16[e] = (u2 + 0x7FFFu + ((u2 >> 16) & 1u)) >> 16;
  }
  uint4 hw, lw;
  unsigned int* hp = &hw.x;
  unsigned int* lp = &lw.x;
#pragma unroll
  for (int w = 0; w < 4; ++w) {
    hp[w] = (hb[2 * w] >> 16) | (hb[2 * w + 1] & 0xFFFF0000u);
    lp[w] = (l16[2 * w] & 0xFFFFu) | (l16[2 * w + 1] << 16);
  }
  hi = __builtin_bit_cast(bf16x8, hw);
  lo = __builtin_bit_cast(bf16x8, lw);
}

// ---------------- fused layer: mean-gather -> LDS -> MFMA GEMM ----------
// out = relu(mean@Wl + b + h@Wr). Grid: 1563 blocks x 64 rows; 256 thr/4 waves.
// Phase 1 (gather): per wave 16 nodes, 2x 32-lane groups, depth-4 neighbor
// pipeline; packed hi/lo mean written to LDS Ml (granule-XOR-swizzled).
// Phase 2 (GEMM): r6 structure; A-fragments from Ml, H from global, B
// double-buffered 8 KB g-tiles via global_load_lds (tile 0 staged in phase 1).
// PACKED_IN: gather src is packed u32 (else f32). HF32: H needs f32 split.
template <int PACKED_IN, int HF32, int OUTF32>
__global__ __launch_bounds__(256, 3) void layer_k(
    const unsigned int* __restrict__ Gp, const int* __restrict__ rowptr,
    const int* __restrict__ col, const unsigned int* __restrict__ Hp,
    const unsigned short* __restrict__ Bp, const float* __restrict__ bias,
    unsigned int* __restrict__ Op, float* __restrict__ Of) {
  __shared__ unsigned int Ml[64 * 128];    // 32 KB packed mean (swizzled)
  __shared__ unsigned short Bl[2][4096];   // 2 x 8 KB B tiles
  const int t = threadIdx.x;
  const int lane = t & 63;
  const int wid = t >> 6;
  const int nblk = blockIdx.x * 64;

  auto stageG = [&](int g, int nb) {
#pragma unroll
    for (int c = 0; c < 2; ++c) {
      const int e = (c * 256 + t) * 8;  // short index
      stage16(Bp + (size_t)g * 4096 + e, &Bl[nb][e]);
    }
  };

  stageG(0, 0);  // B tile 0 rides under the gather phase

  // ---- phase 1: gather mean into LDS ----
  {
    const int grp = lane >> 5;
    const int q = lane & 31;  // uint4 granule 0..31
    const uint4* P = reinterpret_cast<const uint4*>(Gp);
#pragma unroll 1
    for (int n = 0; n < 8; ++n) {
      const int rl = wid * 16 + n * 2 + grp;  // local row 0..63
      const int node = min(nblk + rl, N_NODES - 1);
      const int beg = rowptr[node], end = rowptr[node + 1];
      float a0 = 0.f, a1 = 0.f, a2 = 0.f, a3 = 0.f;
      auto accum = [&](uint4 v) {
        if (PACKED_IN) {
          a0 += __builtin_bit_cast(float, v.x & 0xFFFF0000u);
          a0 += __builtin_bit_cast(float, v.x << 16);
          a1 += __builtin_bit_cast(float, v.y & 0xFFFF0000u);
          a1 += __builtin_bit_cast(float, v.y << 16);
          a2 += __builtin_bit_cast(float, v.z & 0xFFFF0000u);
          a2 += __builtin_bit_cast(float, v.z << 16);
          a3 += __builtin_bit_cast(float, v.w & 0xFFFF0000u);
          a3 += __builtin_bit_cast(float, v.w << 16);
        } else {
          a0 += __builtin_bit_cast(float, v.x);
          a1 += __builtin_bit_cast(float, v.y);
          a2 += __builtin_bit_cast(float, v.z);
          a3 += __builtin_bit_cast(float, v.w);
        }
      };
      for (int i = beg; i < end; i += 4) {
        const int i1 = min(i + 1, end - 1);
        const int i2 = min(i + 2, end - 1);
        const int i3 = min(i + 3, end - 1);
        const int c0 = col[i], c1 = col[i1], c2 = col[i2], c3 = col[i3];
        const uint4 v0 = P[(size_t)c0 * 32 + q];
        const uint4 v1 = P[(size_t)c1 * 32 + q];
        const uint4 v2 = P[(size_t)c2 * 32 + q];
        const uint4 v3 = P[(size_t)c3 * 32 + q];
        accum(v0);
        if (i + 1 < end) accum(v1);
        if (i + 2 < end) accum(v2);
        if (i + 3 < end) accum(v3);
      }
      const int d = end - beg;
      const float inv = 1.0f / (float)(d > 1 ? d : 1);
      uint4 pk;
      pk.x = pack_hl(a0 * inv);
      pk.y = pack_hl(a1 * inv);
      pk.z = pack_hl(a2 * inv);
      pk.w = pack_hl(a3 * inv);
      const int gsw = q ^ (rl & 7);  // granule swizzle vs 512B row stride
      *reinterpret_cast<uint4*>(&Ml[rl * 128 + gsw * 4]) = pk;
    }
  }
  __syncthreads();  // mean ready; B tile 0 ready (vmcnt drained by barrier)

  // ---- phase 2: GEMM ----
  const int lm = lane & 15, lk = lane >> 4;
  const int rbase = nblk + wid * 16;
  const int rlA = wid * 16 + lm;  // local A row
  const size_t r0h = (size_t)min(rbase + lm, N_NODES - 1);
  const uint4* PH = reinterpret_cast<const uint4*>(Hp);

  f32x4 acc[8] = {};

  auto loadPair = [&](int pp, uint4& q0, uint4& q1) {
    if (pp < 4) {
      const int kb = (pp << 3) + (lk << 1);  // even granule 0..30
      const int g0 = kb ^ (rlA & 7);
      const int g1 = (kb + 1) ^ (rlA & 7);
      q0 = *reinterpret_cast<const uint4*>(&Ml[rlA * 128 + g0 * 4]);
      q1 = *reinterpret_cast<const uint4*>(&Ml[rlA * 128 + g1 * 4]);
    } else {
      const int kb = ((pp & 3) << 3) + (lk << 1);
      q0 = PH[r0h * 32 + kb];
      q1 = PH[r0h * 32 + kb + 1];
    }
  };

  uint4 c0, c1, n0, n1;
  loadPair(0, c0, c1);

  bf16x8 fh, fl;
#pragma unroll
  for (int g = 0; g < 16; ++g) {
    const int buf = g & 1;
    if (g < 15) stageG(g + 1, buf ^ 1);
    if ((g & 1) == 0) {
      const int pp = g >> 1;
      if (HF32 && pp >= 4) {
        split_f32(c0, c1, fh, fl);
      } else {
        unpack_pk(c0, c1, fh, fl);
      }
      if (pp < 7) loadPair(pp + 1, n0, n1);  // prefetch next A/H pair
    }
    const bf16x8 fa = (g & 1) ? fl : fh;
#pragma unroll
    for (int nt = 0; nt < 8; ++nt) {
      const bf16x8 b =
          *reinterpret_cast<const bf16x8*>(&Bl[buf][(nt * 64 + lane) * 8]);
      acc[nt] = __builtin_amdgcn_mfma_f32_16x16x32_bf16(fa, b, acc[nt], 0, 0, 0);
    }
    __syncthreads();
    if (g & 1) {
      c0 = n0;
      c1 = n1;
    }
  }

#pragma unroll
  for (int nt = 0; nt < 8; ++nt) {
    const int cidx = nt * 16 + lm;
    const float bv = bias[cidx];
#pragma unroll
    for (int i = 0; i < 4; ++i) {
      const int r = rbase + lk * 4 + i;
      if (r < N_NODES) {
        float v = acc[nt][i] + bv;
        v = fmaxf(v, 0.0f);
        if (OUTF32) {
          Of[(size_t)r * DIM + cidx] = v;
        } else {
          Op[(size_t)r * DIM + cidx] = pack_hl(v);
        }
      }
    }
  }
}

// ---------------- launcher ----------------
extern "C" void kernel_launch(void* const* d_in, const int* in_sizes, int n_in,
                              void* d_out, int out_size, void* d_ws,
                              size_t ws_size, hipStream_t stream) {
  const float* x = (const float*)d_in[0];
  const int* ei = (const int*)d_in[1];
  const float* Wl0 = (const float*)d_in[2];
  const float* bl0 = (const float*)d_in[3];
  const float* Wr0 = (const float*)d_in[4];
  const float* Wl1 = (const float*)d_in[5];
  const float* bl1 = (const float*)d_in[6];
  const float* Wr1 = (const float*)d_in[7];
  float* out = (float*)d_out;
  const int* src = ei;
  const int* dst = ei + N_EDGES;

  char* p = (char*)d_ws;
  auto alloc = [&](size_t bytes) {
    char* q = p;
    p += (bytes + 255) & ~(size_t)255;
    return q;
  };
  int* deg = (int*)alloc((size_t)N_NODES * 4);
  int* rowptr = (int*)alloc((size_t)(N_NODES + 1) * 4);
  int* head = (int*)alloc((size_t)N_NODES * 4);  // doubles as incl-scan temp
  int* col = (int*)alloc((size_t)N_EDGES * 4);
  int* bsum = (int*)alloc(128 * 4);
  int* boffs = (int*)alloc(128 * 4);
  unsigned short* Bp0 = (unsigned short*)alloc(65536 * 2);
  unsigned short* Bp1 = (unsigned short*)alloc(65536 * 2);
  unsigned int* h1p = (unsigned int*)alloc((size_t)N_NODES * DIM * 4);

  const int nScanB = (N_NODES + 1023) / 1024;  // 98

  hipMemsetAsync(deg, 0, (size_t)N_NODES * 4, stream);
  pack_w_k<<<512, 256, 0, stream>>>(Wl0, Wr0, Wl1, Wr1, Bp0, Bp1);
  hist_k<<<(N_EDGES + 255) / 256, 256, 0, stream>>>(dst, deg);
  scan1_k<<<nScanB, 1024, 0, stream>>>(deg, head, bsum);
  scan2_k<<<1, 128, 0, stream>>>(bsum, boffs, nScanB);
  scan3_k<<<nScanB, 1024, 0, stream>>>(deg, head, boffs, rowptr, head);
  fill_k<<<(N_EDGES + 255) / 256, 256, 0, stream>>>(src, dst, head, col);

  const int nBlocks = (N_NODES + 63) / 64;  // 1563

  // layer 0: gather x (f32) -> mean in LDS; GEMM (H = x, f32) -> packed h1p
  layer_k<0, 1, 0><<<nBlocks, 256, 0, stream>>>(
      (const unsigned int*)x, rowptr, col, (const unsigned int*)x, Bp0, bl0,
      h1p, nullptr);
  // layer 1: gather h1p (packed) -> mean in LDS; GEMM (H = h1p) -> f32 out
  layer_k<1, 0, 1><<<nBlocks, 256, 0, stream>>>(h1p, rowptr, col, h1p, Bp1,
                                                bl1, nullptr, out);
}

// Round 8
// 231.649 us; speedup vs baseline: 1.3112x; 1.3112x over previous
//
#include <hip/hip_runtime.h>

#define N_NODES 100000
#define N_EDGES 600000
#define DIM 128

typedef __attribute__((ext_vector_type(8))) short bf16x8;
typedef __attribute__((ext_vector_type(4))) float f32x4;

typedef __attribute__((address_space(1))) const unsigned int g_u32;
typedef __attribute__((address_space(3))) unsigned int l_u32;
__device__ __forceinline__ void stage16(const void* g, void* l) {
  __builtin_amdgcn_global_load_lds((g_u32*)g, (l_u32*)l, 16, 0, 0);
}

__device__ __forceinline__ unsigned short f32_to_bf16_rn(float f) {
  unsigned int u = __builtin_bit_cast(unsigned int, f);
  unsigned int r = (u + 0x7FFFu + ((u >> 16) & 1u)) >> 16;
  return (unsigned short)r;
}
__device__ __forceinline__ float bf16_to_f32(unsigned short h) {
  return __builtin_bit_cast(float, (unsigned int)h << 16);
}

// ---------------- x -> bf16 hi plane ----------------
__global__ __launch_bounds__(256) void xsplit_k(const float* __restrict__ in,
                                                unsigned short* __restrict__ hi) {
  const int i = blockIdx.x * 256 + threadIdx.x;  // one float4 per thread
  const float4 v = reinterpret_cast<const float4*>(in)[i];
  const float f[4] = {v.x, v.y, v.z, v.w};
  unsigned short h[4];
#pragma unroll
  for (int j = 0; j < 4; ++j) h[j] = f32_to_bf16_rn(f[j]);
  uint2 hp;
  hp.x = (unsigned)h[0] | ((unsigned)h[1] << 16);
  hp.y = (unsigned)h[2] | ((unsigned)h[3] << 16);
  reinterpret_cast<uint2*>(hi)[i] = hp;
}

// ---------------- pack BOTH layers' weights into MFMA fragment order -------
// per layer: g-tile sequence (4096 shorts): [Wl_hi k0-31, Wl_lo k0-31, ...,
// Wr_hi..., Wr_lo...]; packed[((g*8+nt)*64+l)*8+j]
__global__ __launch_bounds__(256) void pack_w_k(
    const float* __restrict__ Wl0, const float* __restrict__ Wr0,
    const float* __restrict__ Wl1, const float* __restrict__ Wr1,
    unsigned short* __restrict__ P0, unsigned short* __restrict__ P1) {
  const int gid = blockIdx.x * 256 + threadIdx.x;  // 0..131071
  const int layer = gid >> 16;
  const int idx = gid & 65535;
  const int j = idx & 7;
  const int l = (idx >> 3) & 63;
  const int nt = (idx >> 9) & 7;
  const int g = idx >> 12;
  const int k = (((g >> 1) & 3) << 5) + ((l >> 4) << 3) + j;
  const int n = (nt << 4) + (l & 15);
  const float* W = layer ? ((g < 8) ? Wl1 : Wr1) : ((g < 8) ? Wl0 : Wr0);
  const float w = W[k * 128 + n];
  const unsigned short h = f32_to_bf16_rn(w);
  const unsigned short o = (g & 1) ? f32_to_bf16_rn(w - bf16_to_f32(h)) : h;
  (layer ? P1 : P0)[idx] = o;
}

// ---------------- CSR build ----------------
__global__ void hist_k(const int* __restrict__ dst, int* __restrict__ deg) {
  int e = blockIdx.x * blockDim.x + threadIdx.x;
  if (e < N_EDGES) atomicAdd(&deg[dst[e]], 1);
}

__global__ __launch_bounds__(1024) void scan1_k(const int* __restrict__ deg,
                                                int* __restrict__ incl,
                                                int* __restrict__ bsum) {
  __shared__ int wsum[16];
  const int t = threadIdx.x, lane = t & 63, w = t >> 6;
  const int gi = blockIdx.x * 1024 + t;
  int v = (gi < N_NODES) ? deg[gi] : 0;
  int s = v;
#pragma unroll
  for (int off = 1; off < 64; off <<= 1) {
    int u = __shfl_up(s, off);
    if (lane >= off) s += u;
  }
  if (lane == 63) wsum[w] = s;
  __syncthreads();
  if (t < 16) {
    int ws = wsum[t];
#pragma unroll
    for (int off = 1; off < 16; off <<= 1) {
      int u = __shfl_up(ws, off);
      if (t >= off) ws += u;
    }
    wsum[t] = ws;
  }
  __syncthreads();
  const int val = s + (w ? wsum[w - 1] : 0);
  if (gi < N_NODES) incl[gi] = val;
  if (t == 1023) bsum[blockIdx.x] = val;
}

__global__ void scan2_k(const int* __restrict__ bsum, int* __restrict__ boffs,
                        int nb) {
  __shared__ int w0;
  const int t = threadIdx.x;  // 128 threads
  int v = (t < nb) ? bsum[t] : 0;
  int s = v;
#pragma unroll
  for (int off = 1; off < 64; off <<= 1) {
    int u = __shfl_up(s, off);
    if ((t & 63) >= off) s += u;
  }
  if (t == 63) w0 = s;
  __syncthreads();
  const int excl = s - v + ((t >> 6) ? w0 : 0);
  if (t < nb) boffs[t] = excl;
}

__global__ __launch_bounds__(1024) void scan3_k(const int* __restrict__ deg,
                                                const int* __restrict__ incl,
                                                const int* __restrict__ boffs,
                                                int* __restrict__ rowptr,
                                                int* __restrict__ head) {
  const int gi = blockIdx.x * 1024 + threadIdx.x;
  if (gi < N_NODES) {
    const int e = incl[gi] - deg[gi] + boffs[blockIdx.x];
    rowptr[gi] = e;
    head[gi] = e;
  }
  if (gi == 0) rowptr[N_NODES] = N_EDGES;
}

__global__ void fill_k(const int* __restrict__ src, const int* __restrict__ dst,
                       int* __restrict__ head, int* __restrict__ col) {
  int e = blockIdx.x * blockDim.x + threadIdx.x;
  if (e < N_EDGES) {
    int p = atomicAdd(&head[dst[e]], 1);
    col[p] = src[e];
  }
}

// ---------------- mean aggregation: gather bf16 hi-plane ----------------
// 16 nodes / 256-thread block; 16 lanes per node, 16 B (8 bf16) per lane.
// Depth-4 neighbor pipeline. Output: mean as separate hi + lo bf16 planes.
__global__ __launch_bounds__(256) void agg_k(
    const unsigned short* __restrict__ plane, const int* __restrict__ rowptr,
    const int* __restrict__ col, unsigned short* __restrict__ mhi,
    unsigned short* __restrict__ mlo) {
  const int t = threadIdx.x;
  const int node = blockIdx.x * 16 + (t >> 4);
  const int q = t & 15;  // 16B granule within the 256B row
  const int beg = rowptr[node], end = rowptr[node + 1];
  const uint4* P = reinterpret_cast<const uint4*>(plane);
  float a[8] = {};

  auto accum = [&](uint4 v) {
    const unsigned int u[4] = {v.x, v.y, v.z, v.w};
#pragma unroll
    for (int w = 0; w < 4; ++w) {
      a[2 * w] += __builtin_bit_cast(float, u[w] << 16);
      a[2 * w + 1] += __builtin_bit_cast(float, u[w] & 0xFFFF0000u);
    }
  };

  for (int i = beg; i < end; i += 4) {
    const int i1 = min(i + 1, end - 1);
    const int i2 = min(i + 2, end - 1);
    const int i3 = min(i + 3, end - 1);
    const int c0 = col[i], c1 = col[i1], c2 = col[i2], c3 = col[i3];
    const uint4 v0 = P[(size_t)c0 * 16 + q];
    const uint4 v1 = P[(size_t)c1 * 16 + q];
    const uint4 v2 = P[(size_t)c2 * 16 + q];
    const uint4 v3 = P[(size_t)c3 * 16 + q];
    accum(v0);
    if (i + 1 < end) accum(v1);
    if (i + 2 < end) accum(v2);
    if (i + 3 < end) accum(v3);
  }

  const int d = end - beg;
  const float inv = 1.0f / (float)(d > 1 ? d : 1);
  unsigned int hw[4], lw[4];
#pragma unroll
  for (int w = 0; w < 4; ++w) {
    unsigned short h0, h1, l0, l1;
    const float m0 = a[2 * w] * inv, m1 = a[2 * w + 1] * inv;
    h0 = f32_to_bf16_rn(m0);
    l0 = f32_to_bf16_rn(m0 - bf16_to_f32(h0));
    h1 = f32_to_bf16_rn(m1);
    l1 = f32_to_bf16_rn(m1 - bf16_to_f32(h1));
    hw[w] = (unsigned)h0 | ((unsigned)h1 << 16);
    lw[w] = (unsigned)l0 | ((unsigned)l1 << 16);
  }
  uint4 ho = {hw[0], hw[1], hw[2], hw[3]};
  uint4 lo = {lw[0], lw[1], lw[2], lw[3]};
  reinterpret_cast<uint4*>(mhi)[(size_t)node * 16 + q] = ho;
  reinterpret_cast<uint4*>(mlo)[(size_t)node * 16 + q] = lo;
}

// ---------------- f32 -> hi/lo fragment split (for H = x) ----------------
__device__ __forceinline__ void split_f32(uint4 p0, uint4 p1, bf16x8& hi,
                                          bf16x8& lo) {
  const unsigned int u[8] = {p0.x, p0.y, p0.z, p0.w, p1.x, p1.y, p1.z, p1.w};
  unsigned int hb[8], l16[8];
#pragma unroll
  for (int e = 0; e < 8; ++e) {
    const unsigned int r1 = u[e] + 0x7FFFu + ((u[e] >> 16) & 1u);
    hb[e] = r1 & 0xFFFF0000u;
    const float fl = __builtin_bit_cast(float, u[e]) -
                     __builtin_bit_cast(float, hb[e]);
    const unsigned int u2 = __builtin_bit_cast(unsigned int, fl);
    l16[e] = (u2 + 0x7FFFu + ((u2 >> 16) & 1u)) >> 16;
  }
  uint4 hw, lw;
  unsigned int* hp = &hw.x;
  unsigned int* lp = &lw.x;
#pragma unroll
  for (int w = 0; w < 4; ++w) {
    hp[w] = (hb[2 * w] >> 16) | (hb[2 * w + 1] & 0xFFFF0000u);
    lp[w] = (l16[2 * w] & 0xFFFFu) | (l16[2 * w + 1] << 16);
  }
  hi = __builtin_bit_cast(bf16x8, hw);
  lo = __builtin_bit_cast(bf16x8, lw);
}

// ---------------- MFMA GEMM: out = relu(mean@Wl + b + h@Wr) ----------------
// Grid: 1563 blocks x 64 rows. Block: 256 thr / 4 waves; wave = 16 rows x
// N=128 (8 n-tiles). K loop: 16 g-tiles (hi/lo pairs). B: 8 KB/g-tile,
// double-buffered LDS via global_load_lds, one barrier per g-tile.
// A fragments read directly from mean hi/lo planes; H from x (f32, split) or
// h1 hi/lo planes. Register-prefetched one pair ahead.
template <int HF32, int OUTF32>
__global__ __launch_bounds__(256, 4) void gemm_k(
    const unsigned short* __restrict__ Mhi, const unsigned short* __restrict__ Mlo,
    const float* __restrict__ Hf, const unsigned short* __restrict__ Hhi,
    const unsigned short* __restrict__ Hlo, const unsigned short* __restrict__ Bp,
    const float* __restrict__ bias, unsigned short* __restrict__ Ohi,
    unsigned short* __restrict__ Olo, float* __restrict__ Of) {
  __shared__ unsigned short Bl[2][4096];  // 8 KB per buffer
  const int t = threadIdx.x;
  const int lane = t & 63;
  const int wid = t >> 6;
  const int rbase = blockIdx.x * 64 + wid * 16;
  const int lm = lane & 15, lk = lane >> 4;
  const size_t r0 = (size_t)min(rbase + lm, N_NODES - 1);
  const uint4* PHf = reinterpret_cast<const uint4*>(Hf);

  f32x4 acc[8] = {};

  auto stageG = [&](int g, int nb) {
#pragma unroll
    for (int c = 0; c < 2; ++c) {
      const int e = (c * 256 + t) * 8;  // short index
      stage16(Bp + (size_t)g * 4096 + e, &Bl[nb][e]);
    }
  };
  // load fragments for pair pp: A (pp<4) from mean planes, H (pp>=4)
  auto loadPair = [&](int pp, bf16x8& fh, bf16x8& fl, uint4& q0, uint4& q1) {
    const int ke = ((pp & 3) << 5) + (lk << 3);  // k element offset
    if (pp < 4) {
      fh = *reinterpret_cast<const bf16x8*>(Mhi + r0 * DIM + ke);
      fl = *reinterpret_cast<const bf16x8*>(Mlo + r0 * DIM + ke);
    } else if (HF32) {
      q0 = PHf[r0 * 32 + (ke >> 2)];
      q1 = PHf[r0 * 32 + (ke >> 2) + 1];
    } else {
      fh = *reinterpret_cast<const bf16x8*>(Hhi + r0 * DIM + ke);
      fl = *reinterpret_cast<const bf16x8*>(Hlo + r0 * DIM + ke);
    }
  };

  bf16x8 ch, cl, nh, nl;
  uint4 cq0, cq1, nq0, nq1;
  stageG(0, 0);
  loadPair(0, ch, cl, cq0, cq1);
  __syncthreads();

  bf16x8 fh, fl;
#pragma unroll
  for (int g = 0; g < 16; ++g) {
    const int buf = g & 1;
    if (g < 15) stageG(g + 1, buf ^ 1);
    if ((g & 1) == 0) {
      const int pp = g >> 1;
      if (HF32 && pp >= 4) {
        split_f32(cq0, cq1, fh, fl);
      } else {
        fh = ch;
        fl = cl;
      }
      if (pp < 7) loadPair(pp + 1, nh, nl, nq0, nq1);  // prefetch next pair
    }
    const bf16x8 fa = (g & 1) ? fl : fh;
#pragma unroll
    for (int nt = 0; nt < 8; ++nt) {
      const bf16x8 b =
          *reinterpret_cast<const bf16x8*>(&Bl[buf][(nt * 64 + lane) * 8]);
      acc[nt] = __builtin_amdgcn_mfma_f32_16x16x32_bf16(fa, b, acc[nt], 0, 0, 0);
    }
    __syncthreads();
    if (g & 1) {
      ch = nh;
      cl = nl;
      cq0 = nq0;
      cq1 = nq1;
    }
  }

#pragma unroll
  for (int nt = 0; nt < 8; ++nt) {
    const int cidx = nt * 16 + lm;
    const float bv = bias[cidx];
#pragma unroll
    for (int i = 0; i < 4; ++i) {
      const int r = rbase + lk * 4 + i;
      if (r < N_NODES) {
        float v = acc[nt][i] + bv;
        v = fmaxf(v, 0.0f);
        if (OUTF32) {
          Of[(size_t)r * DIM + cidx] = v;
        } else {
          const unsigned short h = f32_to_bf16_rn(v);
          Ohi[(size_t)r * DIM + cidx] = h;
          Olo[(size_t)r * DIM + cidx] = f32_to_bf16_rn(v - bf16_to_f32(h));
        }
      }
    }
  }
}

// ---------------- launcher ----------------
extern "C" void kernel_launch(void* const* d_in, const int* in_sizes, int n_in,
                              void* d_out, int out_size, void* d_ws,
                              size_t ws_size, hipStream_t stream) {
  const float* x = (const float*)d_in[0];
  const int* ei = (const int*)d_in[1];
  const float* Wl0 = (const float*)d_in[2];
  const float* bl0 = (const float*)d_in[3];
  const float* Wr0 = (const float*)d_in[4];
  const float* Wl1 = (const float*)d_in[5];
  const float* bl1 = (const float*)d_in[6];
  const float* Wr1 = (const float*)d_in[7];
  float* out = (float*)d_out;
  const int* src = ei;
  const int* dst = ei + N_EDGES;

  char* p = (char*)d_ws;
  auto alloc = [&](size_t bytes) {
    char* q = p;
    p += (bytes + 255) & ~(size_t)255;
    return q;
  };
  int* deg = (int*)alloc((size_t)N_NODES * 4);
  int* rowptr = (int*)alloc((size_t)(N_NODES + 1) * 4);
  int* head = (int*)alloc((size_t)N_NODES * 4);  // doubles as incl-scan temp
  int* col = (int*)alloc((size_t)N_EDGES * 4);
  int* bsum = (int*)alloc(128 * 4);
  int* boffs = (int*)alloc(128 * 4);
  unsigned short* Bp0 = (unsigned short*)alloc(65536 * 2);
  unsigned short* Bp1 = (unsigned short*)alloc(65536 * 2);
  unsigned short* xhi = (unsigned short*)alloc((size_t)N_NODES * DIM * 2);
  unsigned short* mhi = (unsigned short*)alloc((size_t)N_NODES * DIM * 2);
  unsigned short* mlo = (unsigned short*)alloc((size_t)N_NODES * DIM * 2);
  unsigned short* h1hi = (unsigned short*)alloc((size_t)N_NODES * DIM * 2);
  unsigned short* h1lo = (unsigned short*)alloc((size_t)N_NODES * DIM * 2);

  const int nScanB = (N_NODES + 1023) / 1024;  // 98

  hipMemsetAsync(deg, 0, (size_t)N_NODES * 4, stream);
  pack_w_k<<<512, 256, 0, stream>>>(Wl0, Wr0, Wl1, Wr1, Bp0, Bp1);
  xsplit_k<<<(N_NODES * DIM / 4) / 256, 256, 0, stream>>>(x, xhi);
  hist_k<<<(N_EDGES + 255) / 256, 256, 0, stream>>>(dst, deg);
  scan1_k<<<nScanB, 1024, 0, stream>>>(deg, head, bsum);
  scan2_k<<<1, 128, 0, stream>>>(bsum, boffs, nScanB);
  scan3_k<<<nScanB, 1024, 0, stream>>>(deg, head, boffs, rowptr, head);
  fill_k<<<(N_EDGES + 255) / 256, 256, 0, stream>>>(src, dst, head, col);

  const int nBlocks = (N_NODES + 63) / 64;    // 1563
  const int aggBlocks = N_NODES / 16;         // 6250

  // layer 0: gather xhi -> mean planes; gemm0 (H = x f32) -> h1 planes
  agg_k<<<aggBlocks, 256, 0, stream>>>(xhi, rowptr, col, mhi, mlo);
  gemm_k<1, 0><<<nBlocks, 256, 0, stream>>>(mhi, mlo, x, nullptr, nullptr,
                                            Bp0, bl0, h1hi, h1lo, nullptr);
  // layer 1: gather h1hi -> mean planes; gemm1 (H = h1 planes) -> f32 out
  agg_k<<<aggBlocks, 256, 0, stream>>>(h1hi, rowptr, col, mhi, mlo);
  gemm_k<0, 1><<<nBlocks, 256, 0, stream>>>(mhi, mlo, nullptr, h1hi, h1lo,
                                            Bp1, bl1, nullptr, nullptr, out);
}

// Round 9
// 183.970 us; speedup vs baseline: 1.6510x; 1.2592x over previous
//
#include <hip/hip_runtime.h>

#define N_NODES 100000
#define N_EDGES 600000
#define DIM 128

typedef __attribute__((ext_vector_type(8))) short bf16x8;
typedef __attribute__((ext_vector_type(4))) float f32x4;

typedef __attribute__((address_space(1))) const unsigned int g_u32;
typedef __attribute__((address_space(3))) unsigned int l_u32;
__device__ __forceinline__ void stage16(const void* g, void* l) {
  __builtin_amdgcn_global_load_lds((g_u32*)g, (l_u32*)l, 16, 0, 0);
}

__device__ __forceinline__ unsigned short f32_to_bf16_rn(float f) {
  unsigned int u = __builtin_bit_cast(unsigned int, f);
  unsigned int r = (u + 0x7FFFu + ((u >> 16) & 1u)) >> 16;
  return (unsigned short)r;
}
__device__ __forceinline__ float bf16_to_f32(unsigned short h) {
  return __builtin_bit_cast(float, (unsigned int)h << 16);
}

// ---------------- x -> bf16 hi plane ----------------
__global__ __launch_bounds__(256) void xsplit_k(const float* __restrict__ in,
                                                unsigned short* __restrict__ hi) {
  const int i = blockIdx.x * 256 + threadIdx.x;  // one float4 per thread
  const float4 v = reinterpret_cast<const float4*>(in)[i];
  const float f[4] = {v.x, v.y, v.z, v.w};
  unsigned short h[4];
#pragma unroll
  for (int j = 0; j < 4; ++j) h[j] = f32_to_bf16_rn(f[j]);
  uint2 hp;
  hp.x = (unsigned)h[0] | ((unsigned)h[1] << 16);
  hp.y = (unsigned)h[2] | ((unsigned)h[3] << 16);
  reinterpret_cast<uint2*>(hi)[i] = hp;
}

// ---------------- pack BOTH layers' weights (hi only) -------
// per layer: 8 g-tiles (4096 shorts each): g 0-3 = Wl k-tiles 0-3,
// g 4-7 = Wr k-tiles 0-3; packed[((g*8+nt)*64+l)*8+j] =
// W[(g&3)*32 + (l>>4)*8 + j][nt*16 + (l&15)]
__global__ __launch_bounds__(256) void pack_w_k(
    const float* __restrict__ Wl0, const float* __restrict__ Wr0,
    const float* __restrict__ Wl1, const float* __restrict__ Wr1,
    unsigned short* __restrict__ P0, unsigned short* __restrict__ P1) {
  const int gid = blockIdx.x * 256 + threadIdx.x;  // 0..65535
  const int layer = gid >> 15;
  const int idx = gid & 32767;
  const int j = idx & 7;
  const int l = (idx >> 3) & 63;
  const int nt = (idx >> 9) & 7;
  const int g = idx >> 12;  // 0..7
  const int k = ((g & 3) << 5) + ((l >> 4) << 3) + j;
  const int n = (nt << 4) + (l & 15);
  const float* W = layer ? ((g < 4) ? Wl1 : Wr1) : ((g < 4) ? Wl0 : Wr0);
  (layer ? P1 : P0)[idx] = f32_to_bf16_rn(W[k * 128 + n]);
}

// ---------------- CSR build ----------------
__global__ void hist_k(const int* __restrict__ dst, int* __restrict__ deg) {
  int e = blockIdx.x * blockDim.x + threadIdx.x;
  if (e < N_EDGES) atomicAdd(&deg[dst[e]], 1);
}

__global__ __launch_bounds__(1024) void scan1_k(const int* __restrict__ deg,
                                                int* __restrict__ incl,
                                                int* __restrict__ bsum) {
  __shared__ int wsum[16];
  const int t = threadIdx.x, lane = t & 63, w = t >> 6;
  const int gi = blockIdx.x * 1024 + t;
  int v = (gi < N_NODES) ? deg[gi] : 0;
  int s = v;
#pragma unroll
  for (int off = 1; off < 64; off <<= 1) {
    int u = __shfl_up(s, off);
    if (lane >= off) s += u;
  }
  if (lane == 63) wsum[w] = s;
  __syncthreads();
  if (t < 16) {
    int ws = wsum[t];
#pragma unroll
    for (int off = 1; off < 16; off <<= 1) {
      int u = __shfl_up(ws, off);
      if (t >= off) ws += u;
    }
    wsum[t] = ws;
  }
  __syncthreads();
  const int val = s + (w ? wsum[w - 1] : 0);
  if (gi < N_NODES) incl[gi] = val;
  if (t == 1023) bsum[blockIdx.x] = val;
}

__global__ void scan2_k(const int* __restrict__ bsum, int* __restrict__ boffs,
                        int nb) {
  __shared__ int w0;
  const int t = threadIdx.x;  // 128 threads
  int v = (t < nb) ? bsum[t] : 0;
  int s = v;
#pragma unroll
  for (int off = 1; off < 64; off <<= 1) {
    int u = __shfl_up(s, off);
    if ((t & 63) >= off) s += u;
  }
  if (t == 63) w0 = s;
  __syncthreads();
  const int excl = s - v + ((t >> 6) ? w0 : 0);
  if (t < nb) boffs[t] = excl;
}

__global__ __launch_bounds__(1024) void scan3_k(const int* __restrict__ deg,
                                                const int* __restrict__ incl,
                                                const int* __restrict__ boffs,
                                                int* __restrict__ rowptr,
                                                int* __restrict__ head) {
  const int gi = blockIdx.x * 1024 + threadIdx.x;
  if (gi < N_NODES) {
    const int e = incl[gi] - deg[gi] + boffs[blockIdx.x];
    rowptr[gi] = e;
    head[gi] = e;
  }
  if (gi == 0) rowptr[N_NODES] = N_EDGES;
}

__global__ void fill_k(const int* __restrict__ src, const int* __restrict__ dst,
                       int* __restrict__ head, int* __restrict__ col) {
  int e = blockIdx.x * blockDim.x + threadIdx.x;
  if (e < N_EDGES) {
    int p = atomicAdd(&head[dst[e]], 1);
    col[p] = src[e];
  }
}

// ---------------- mean aggregation: gather bf16 hi-plane ----------------
// 16 nodes / 256-thread block; 16 lanes per node, 16 B (8 bf16) per lane.
// Depth-4 neighbor pipeline. Output: mean as bf16 hi plane.
__global__ __launch_bounds__(256) void agg_k(
    const unsigned short* __restrict__ plane, const int* __restrict__ rowptr,
    const int* __restrict__ col, unsigned short* __restrict__ mhi) {
  const int t = threadIdx.x;
  const int node = blockIdx.x * 16 + (t >> 4);
  const int q = t & 15;  // 16B granule within the 256B row
  const int beg = rowptr[node], end = rowptr[node + 1];
  const uint4* P = reinterpret_cast<const uint4*>(plane);
  float a[8] = {};

  auto accum = [&](uint4 v) {
    const unsigned int u[4] = {v.x, v.y, v.z, v.w};
#pragma unroll
    for (int w = 0; w < 4; ++w) {
      a[2 * w] += __builtin_bit_cast(float, u[w] << 16);
      a[2 * w + 1] += __builtin_bit_cast(float, u[w] & 0xFFFF0000u);
    }
  };

  for (int i = beg; i < end; i += 4) {
    const int i1 = min(i + 1, end - 1);
    const int i2 = min(i + 2, end - 1);
    const int i3 = min(i + 3, end - 1);
    const int c0 = col[i], c1 = col[i1], c2 = col[i2], c3 = col[i3];
    const uint4 v0 = P[(size_t)c0 * 16 + q];
    const uint4 v1 = P[(size_t)c1 * 16 + q];
    const uint4 v2 = P[(size_t)c2 * 16 + q];
    const uint4 v3 = P[(size_t)c3 * 16 + q];
    accum(v0);
    if (i + 1 < end) accum(v1);
    if (i + 2 < end) accum(v2);
    if (i + 3 < end) accum(v3);
  }

  const int d = end - beg;
  const float inv = 1.0f / (float)(d > 1 ? d : 1);
  unsigned int hw[4];
#pragma unroll
  for (int w = 0; w < 4; ++w) {
    const unsigned short h0 = f32_to_bf16_rn(a[2 * w] * inv);
    const unsigned short h1 = f32_to_bf16_rn(a[2 * w + 1] * inv);
    hw[w] = (unsigned)h0 | ((unsigned)h1 << 16);
  }
  uint4 ho = {hw[0], hw[1], hw[2], hw[3]};
  reinterpret_cast<uint4*>(mhi)[(size_t)node * 16 + q] = ho;
}

// ---------------- MFMA GEMM: out = relu(mean@Wl + b + h@Wr) ----------------
// Grid: 1563 blocks x 64 rows. Block: 256 thr / 4 waves; wave = 16 rows x
// N=128 (8 n-tiles). K loop: 8 g-tiles (g 0-3: Mhi x Wl; g 4-7: Hhi x Wr).
// B: 8 KB/g-tile, double-buffered LDS via global_load_lds, one barrier per
// g-tile. A fragment = direct bf16x8 load, register-prefetched one ahead.
template <int OUTF32>
__global__ __launch_bounds__(256, 4) void gemm_k(
    const unsigned short* __restrict__ Mhi, const unsigned short* __restrict__ Hhi,
    const unsigned short* __restrict__ Bp, const float* __restrict__ bias,
    unsigned short* __restrict__ Ohi, float* __restrict__ Of) {
  __shared__ unsigned short Bl[2][4096];  // 8 KB per buffer
  const int t = threadIdx.x;
  const int lane = t & 63;
  const int wid = t >> 6;
  const int rbase = blockIdx.x * 64 + wid * 16;
  const int lm = lane & 15, lk = lane >> 4;
  const size_t r0 = (size_t)min(rbase + lm, N_NODES - 1);

  f32x4 acc[8] = {};

  auto stageG = [&](int g, int nb) {
#pragma unroll
    for (int c = 0; c < 2; ++c) {
      const int e = (c * 256 + t) * 8;  // short index
      stage16(Bp + (size_t)g * 4096 + e, &Bl[nb][e]);
    }
  };
  auto loadA = [&](int g) {
    const unsigned short* P = (g < 4) ? Mhi : Hhi;
    const int ke = ((g & 3) << 5) + (lk << 3);
    return *reinterpret_cast<const bf16x8*>(P + r0 * DIM + ke);
  };

  stageG(0, 0);
  bf16x8 ca = loadA(0), na;
  __syncthreads();

#pragma unroll
  for (int g = 0; g < 8; ++g) {
    const int buf = g & 1;
    if (g < 7) {
      stageG(g + 1, buf ^ 1);
      na = loadA(g + 1);
    }
#pragma unroll
    for (int nt = 0; nt < 8; ++nt) {
      const bf16x8 b =
          *reinterpret_cast<const bf16x8*>(&Bl[buf][(nt * 64 + lane) * 8]);
      acc[nt] = __builtin_amdgcn_mfma_f32_16x16x32_bf16(ca, b, acc[nt], 0, 0, 0);
    }
    __syncthreads();
    ca = na;
  }

#pragma unroll
  for (int nt = 0; nt < 8; ++nt) {
    const int cidx = nt * 16 + lm;
    const float bv = bias[cidx];
#pragma unroll
    for (int i = 0; i < 4; ++i) {
      const int r = rbase + lk * 4 + i;
      if (r < N_NODES) {
        float v = acc[nt][i] + bv;
        v = fmaxf(v, 0.0f);
        if (OUTF32) {
          Of[(size_t)r * DIM + cidx] = v;
        } else {
          Ohi[(size_t)r * DIM + cidx] = f32_to_bf16_rn(v);
        }
      }
    }
  }
}

// ---------------- launcher ----------------
extern "C" void kernel_launch(void* const* d_in, const int* in_sizes, int n_in,
                              void* d_out, int out_size, void* d_ws,
                              size_t ws_size, hipStream_t stream) {
  const float* x = (const float*)d_in[0];
  const int* ei = (const int*)d_in[1];
  const float* Wl0 = (const float*)d_in[2];
  const float* bl0 = (const float*)d_in[3];
  const float* Wr0 = (const float*)d_in[4];
  const float* Wl1 = (const float*)d_in[5];
  const float* bl1 = (const float*)d_in[6];
  const float* Wr1 = (const float*)d_in[7];
  float* out = (float*)d_out;
  const int* src = ei;
  const int* dst = ei + N_EDGES;

  char* p = (char*)d_ws;
  auto alloc = [&](size_t bytes) {
    char* q = p;
    p += (bytes + 255) & ~(size_t)255;
    return q;
  };
  int* deg = (int*)alloc((size_t)N_NODES * 4);
  int* rowptr = (int*)alloc((size_t)(N_NODES + 1) * 4);
  int* head = (int*)alloc((size_t)N_NODES * 4);  // doubles as incl-scan temp
  int* col = (int*)alloc((size_t)N_EDGES * 4);
  int* bsum = (int*)alloc(128 * 4);
  int* boffs = (int*)alloc(128 * 4);
  unsigned short* Bp0 = (unsigned short*)alloc(32768 * 2);
  unsigned short* Bp1 = (unsigned short*)alloc(32768 * 2);
  unsigned short* xhi = (unsigned short*)alloc((size_t)N_NODES * DIM * 2);
  unsigned short* mhi = (unsigned short*)alloc((size_t)N_NODES * DIM * 2);
  unsigned short* h1hi = (unsigned short*)alloc((size_t)N_NODES * DIM * 2);

  const int nScanB = (N_NODES + 1023) / 1024;  // 98

  hipMemsetAsync(deg, 0, (size_t)N_NODES * 4, stream);
  pack_w_k<<<256, 256, 0, stream>>>(Wl0, Wr0, Wl1, Wr1, Bp0, Bp1);
  xsplit_k<<<(N_NODES * DIM / 4) / 256, 256, 0, stream>>>(x, xhi);
  hist_k<<<(N_EDGES + 255) / 256, 256, 0, stream>>>(dst, deg);
  scan1_k<<<nScanB, 1024, 0, stream>>>(deg, head, bsum);
  scan2_k<<<1, 128, 0, stream>>>(bsum, boffs, nScanB);
  scan3_k<<<nScanB, 1024, 0, stream>>>(deg, head, boffs, rowptr, head);
  fill_k<<<(N_EDGES + 255) / 256, 256, 0, stream>>>(src, dst, head, col);

  const int nBlocks = (N_NODES + 63) / 64;    // 1563
  const int aggBlocks = N_NODES / 16;         // 6250

  // layer 0: gather xhi -> mhi; gemm0 (A = mhi, H = xhi) -> h1hi
  agg_k<<<aggBlocks, 256, 0, stream>>>(xhi, rowptr, col, mhi);
  gemm_k<0><<<nBlocks, 256, 0, stream>>>(mhi, xhi, Bp0, bl0, h1hi, nullptr);
  // layer 1: gather h1hi -> mhi; gemm1 (A = mhi, H = h1hi) -> f32 out
  agg_k<<<aggBlocks, 256, 0, stream>>>(h1hi, rowptr, col, mhi);
  gemm_k<1><<<nBlocks, 256, 0, stream>>>(mhi, h1hi, Bp1, bl1, nullptr, out);
}